// Round 2
// baseline (666.447 us; speedup 1.0000x reference)
//
#include <hip/hip_runtime.h>
#include <math.h>

#define N_NODES 40000
#define DEG 16
#define DIN 128
#define NH 8
#define DH 16
#define FFDIM 512
#define ALPHA 0.15f
#define LNEPS 1e-5f

// ---------------- wave helpers (wave = 64) ----------------
__device__ inline float wave_sum64(float v) {
#pragma unroll
    for (int m = 32; m >= 1; m >>= 1) v += __shfl_xor(v, m, 64);
    return v;
}

// ---------------- LayerNorm: one wave per node ----------------
__global__ void ln_kernel(const float* __restrict__ in, const float* __restrict__ g,
                          const float* __restrict__ b, float* __restrict__ out, int n) {
    int wid  = (blockIdx.x * blockDim.x + threadIdx.x) >> 6;
    int lane = threadIdx.x & 63;
    if (wid >= n) return;
    float2 v = *(const float2*)(in + (size_t)wid * DIN + lane * 2);
    float mean = wave_sum64(v.x + v.y) * (1.0f / DIN);
    float dx = v.x - mean, dy = v.y - mean;
    float var = wave_sum64(dx * dx + dy * dy) * (1.0f / DIN);
    float rstd = rsqrtf(var + LNEPS);
    float2 gg = *(const float2*)(g + lane * 2);
    float2 bb = *(const float2*)(b + lane * 2);
    float2 o = { dx * rstd * gg.x + bb.x, dy * rstd * gg.y + bb.y };
    *(float2*)(out + (size_t)wid * DIN + lane * 2) = o;
}

// rst = f + feat (written to d_out), x = LN(rst)
__global__ void add_ln_kernel(const float* __restrict__ f, const float* __restrict__ feat,
                              const float* __restrict__ g, const float* __restrict__ b,
                              float* __restrict__ rst, float* __restrict__ x, int n) {
    int wid  = (blockIdx.x * blockDim.x + threadIdx.x) >> 6;
    int lane = threadIdx.x & 63;
    if (wid >= n) return;
    float2 va = *(const float2*)(f + (size_t)wid * DIN + lane * 2);
    float2 vb = *(const float2*)(feat + (size_t)wid * DIN + lane * 2);
    float2 r = { va.x + vb.x, va.y + vb.y };
    *(float2*)(rst + (size_t)wid * DIN + lane * 2) = r;
    float mean = wave_sum64(r.x + r.y) * (1.0f / DIN);
    float dx = r.x - mean, dy = r.y - mean;
    float var = wave_sum64(dx * dx + dy * dy) * (1.0f / DIN);
    float rstd = rsqrtf(var + LNEPS);
    float2 gg = *(const float2*)(g + lane * 2);
    float2 bb = *(const float2*)(b + lane * 2);
    float2 o = { dx * rstd * gg.x + bb.x, dy * rstd * gg.y + bb.y };
    *(float2*)(x + (size_t)wid * DIN + lane * 2) = o;
}

// ---------------- generic fp32 GEMM: C = act(A @ B^T + bias) + res ----------------
// A[M,K] row-major, B[Nn,K] row-major. M%64==0, Nn%64==0, K%64==0.
__global__ __launch_bounds__(256) void gemm_bt(
        const float* __restrict__ A, const float* __restrict__ B, float* __restrict__ C,
        const float* __restrict__ bias, const float* __restrict__ res, int relu,
        int M, int Nn, int K) {
    __shared__ float As[64][68];
    __shared__ float Bs[64][68];
    const int bm = blockIdx.x * 64;
    const int bn = blockIdx.y * 64;
    const int t  = threadIdx.x;
    const int tx = t & 15, ty = t >> 4;
    float acc[4][4] = {};
    for (int k0 = 0; k0 < K; k0 += 64) {
        __syncthreads();
#pragma unroll
        for (int q = 0; q < 4; ++q) {
            int lin = t + q * 256;
            int row = lin >> 4;
            int kf  = (lin & 15) << 2;
            float4 va = *(const float4*)(A + (size_t)(bm + row) * K + k0 + kf);
            As[kf + 0][row] = va.x; As[kf + 1][row] = va.y;
            As[kf + 2][row] = va.z; As[kf + 3][row] = va.w;
            float4 vb = *(const float4*)(B + (size_t)(bn + row) * K + k0 + kf);
            Bs[kf + 0][row] = vb.x; Bs[kf + 1][row] = vb.y;
            Bs[kf + 2][row] = vb.z; Bs[kf + 3][row] = vb.w;
        }
        __syncthreads();
#pragma unroll 8
        for (int kk = 0; kk < 64; ++kk) {
            float4 a4 = *(const float4*)&As[kk][ty * 4];
            float4 b4 = *(const float4*)&Bs[kk][tx * 4];
            float ar[4] = { a4.x, a4.y, a4.z, a4.w };
            float br[4] = { b4.x, b4.y, b4.z, b4.w };
#pragma unroll
            for (int i = 0; i < 4; ++i)
#pragma unroll
                for (int j = 0; j < 4; ++j) acc[i][j] += ar[i] * br[j];
        }
    }
    float4 bv = { 0, 0, 0, 0 };
    if (bias) bv = *(const float4*)(bias + bn + tx * 4);
#pragma unroll
    for (int i = 0; i < 4; ++i) {
        size_t row = (size_t)(bm + ty * 4 + i);
        int col = bn + tx * 4;
        float4 v = { acc[i][0] + bv.x, acc[i][1] + bv.y, acc[i][2] + bv.z, acc[i][3] + bv.w };
        if (relu) {
            v.x = fmaxf(v.x, 0.f); v.y = fmaxf(v.y, 0.f);
            v.z = fmaxf(v.z, 0.f); v.w = fmaxf(v.w, 0.f);
        }
        if (res) {
            float4 r = *(const float4*)(res + row * Nn + col);
            v.x += r.x; v.y += r.y; v.z += r.z; v.w += r.w;
        }
        *(float4*)(C + row * Nn + col) = v;
    }
}

// ---------------- fused 3-way projection: one launch for Wh/Wt/We ----------------
// blockIdx.y in [0,6): matrix = y>>1, column block = y&1. K = Nn = DIN = 128.
__global__ __launch_bounds__(256) void proj3_gemm(
        const float* __restrict__ A,
        const float* __restrict__ W0, const float* __restrict__ W1w, const float* __restrict__ W2w,
        float* __restrict__ C0, float* __restrict__ C1c, float* __restrict__ C2c,
        int M) {
    __shared__ float As[64][68];
    __shared__ float Bs[64][68];
    const int bm  = blockIdx.x * 64;
    const int sel = blockIdx.y >> 1;
    const int bn  = (blockIdx.y & 1) * 64;
    const float* B = (sel == 0) ? W0 : (sel == 1) ? W1w : W2w;
    float* C       = (sel == 0) ? C0 : (sel == 1) ? C1c : C2c;
    const int t  = threadIdx.x;
    const int tx = t & 15, ty = t >> 4;
    float acc[4][4] = {};
    for (int k0 = 0; k0 < DIN; k0 += 64) {
        __syncthreads();
#pragma unroll
        for (int q = 0; q < 4; ++q) {
            int lin = t + q * 256;
            int row = lin >> 4;
            int kf  = (lin & 15) << 2;
            float4 va = *(const float4*)(A + (size_t)(bm + row) * DIN + k0 + kf);
            As[kf + 0][row] = va.x; As[kf + 1][row] = va.y;
            As[kf + 2][row] = va.z; As[kf + 3][row] = va.w;
            float4 vb = *(const float4*)(B + (size_t)(bn + row) * DIN + k0 + kf);
            Bs[kf + 0][row] = vb.x; Bs[kf + 1][row] = vb.y;
            Bs[kf + 2][row] = vb.z; Bs[kf + 3][row] = vb.w;
        }
        __syncthreads();
#pragma unroll 8
        for (int kk = 0; kk < 64; ++kk) {
            float4 a4 = *(const float4*)&As[kk][ty * 4];
            float4 b4 = *(const float4*)&Bs[kk][tx * 4];
            float ar[4] = { a4.x, a4.y, a4.z, a4.w };
            float br[4] = { b4.x, b4.y, b4.z, b4.w };
#pragma unroll
            for (int i = 0; i < 4; ++i)
#pragma unroll
                for (int j = 0; j < 4; ++j) acc[i][j] += ar[i] * br[j];
        }
    }
#pragma unroll
    for (int i = 0; i < 4; ++i) {
        size_t row = (size_t)(bm + ty * 4 + i);
        int col = bn + tx * 4;
        float4 v = { acc[i][0], acc[i][1], acc[i][2], acc[i][3] };
        *(float4*)(C + row * DIN + col) = v;
    }
}

// ---------------- gate scores gh/gt: thread per (node, head) ----------------
__global__ void gates_kernel(const float* __restrict__ fh, const float* __restrict__ ftl,
                             const float* __restrict__ g_head, const float* __restrict__ g_tail,
                             float* __restrict__ gh, float* __restrict__ gt, int total) {
    int t = blockIdx.x * blockDim.x + threadIdx.x;
    if (t >= total) return;
    int i = t >> 3, h = t & 7;
    const float4* fp = (const float4*)(fh + (size_t)i * DIN + h * DH);
    const float4* gp = (const float4*)(g_head + h * DH);
    const float4* fq = (const float4*)(ftl + (size_t)i * DIN + h * DH);
    const float4* gq = (const float4*)(g_tail + h * DH);
    float s1 = 0.f, s2 = 0.f;
#pragma unroll
    for (int q = 0; q < 4; ++q) {
        float4 a = fp[q], b = gp[q];
        s1 += a.x * b.x + a.y * b.y + a.z * b.z + a.w * b.w;
        float4 c = fq[q], d = gq[q];
        s2 += c.x * d.x + c.y * d.y + c.z * d.z + c.w * d.w;
    }
    gh[t] = s1;
    gt[t] = s2;
}

// ---------------- edge attention + softmax: one wave per dst node ----------------
__global__ void attn_kernel(const float* __restrict__ fh, const float* __restrict__ ftl,
                            const float* __restrict__ ghv, const float* __restrict__ gtv,
                            const float* __restrict__ attn_p, const int* __restrict__ src,
                            float* __restrict__ av, int n) {
    int wid  = (blockIdx.x * blockDim.x + threadIdx.x) >> 6;
    int lane = threadIdx.x & 63;
    if (wid >= n) return;
    int e  = lane & 15;
    int h0 = lane >> 4;
    int s = src[(size_t)wid * DEG + e];
    const float4* fhs = (const float4*)(fh + (size_t)s * DIN);
    const float4* fti = (const float4*)(ftl + (size_t)wid * DIN);
    const float4* ap  = (const float4*)attn_p;
    float v0 = 0.f, v1 = 0.f;
#pragma unroll
    for (int q = 0; q < 4; ++q) {
        float4 xa = fhs[h0 * 4 + q], xb = fti[h0 * 4 + q], xc = ap[h0 * 4 + q];
        v0 += xa.x * xb.x * xc.x + xa.y * xb.y * xc.y + xa.z * xb.z * xc.z + xa.w * xb.w * xc.w;
        float4 ya = fhs[(h0 + 4) * 4 + q], yb = fti[(h0 + 4) * 4 + q], yc = ap[(h0 + 4) * 4 + q];
        v1 += ya.x * yb.x * yc.x + ya.y * yb.y * yc.y + ya.z * yb.z * yc.z + ya.w * yb.w * yc.w;
    }
    const float c = 0.17328679513998632f;  // ln(16)/16  (in_deg == 16 structurally)
    v0 *= c; v1 *= c;
    float m0 = v0, m1 = v1;
#pragma unroll
    for (int msk = 1; msk <= 8; msk <<= 1) {
        m0 = fmaxf(m0, __shfl_xor(m0, msk, 64));
        m1 = fmaxf(m1, __shfl_xor(m1, msk, 64));
    }
    float gate0 = 1.f / (1.f + expf(-(ghv[(size_t)s * NH + h0]     + gtv[(size_t)wid * NH + h0])));
    float gate1 = 1.f / (1.f + expf(-(ghv[(size_t)s * NH + h0 + 4] + gtv[(size_t)wid * NH + h0 + 4])));
    float t0 = expf(v0 - m0) * gate0;
    float t1 = expf(v1 - m1) * gate1;
    float s0 = t0, s1 = t1;
#pragma unroll
    for (int msk = 1; msk <= 8; msk <<= 1) {
        s0 += __shfl_xor(s0, msk, 64);
        s1 += __shfl_xor(s1, msk, 64);
    }
    float* ao = av + ((size_t)wid * DEG + e) * NH;
    ao[h0]     = t0 / s0;
    ao[h0 + 4] = t1 / s1;
}

// ---------------- one PPR hop ----------------
// Block = 256 threads = 4 waves = 4 nodes. Src indices staged via LDS once per block.
__global__ __launch_bounds__(256) void hop_kernel(
        const float* __restrict__ fin, const float* __restrict__ fe,
        const float* __restrict__ av, const int* __restrict__ src,
        float* __restrict__ fout, int n) {
    __shared__ int sidx[4 * DEG];
    int wv   = threadIdx.x >> 6;           // wave in block: 0..3
    int lane = threadIdx.x & 63;
    int wid  = blockIdx.x * 4 + wv;
    if (threadIdx.x < 4 * DEG) {
        int node = blockIdx.x * 4 + (threadIdx.x >> 4);
        sidx[threadIdx.x] = (node < n) ? src[(size_t)node * DEG + (threadIdx.x & 15)] : 0;
    }
    __syncthreads();
    if (wid >= n) return;
    int h = lane >> 3;
    const float* ae = av + (size_t)wid * DEG * NH;
    const int* se = &sidx[wv * DEG];
    float ax = 0.f, ay = 0.f;
#pragma unroll
    for (int e = 0; e < DEG; ++e) {
        int s = se[e];
        float w = ae[e * NH + h];
        float2 fv = *(const float2*)(fin + (size_t)s * DIN + lane * 2);
        ax += w * fv.x; ay += w * fv.y;
    }
    float2 fev = *(const float2*)(fe + (size_t)wid * DIN + lane * 2);
    float2 o = { (1.f - ALPHA) * ax + ALPHA * fev.x, (1.f - ALPHA) * ay + ALPHA * fev.y };
    *(float2*)(fout + (size_t)wid * DIN + lane * 2) = o;
}

extern "C" void kernel_launch(void* const* d_in, const int* in_sizes, int n_in,
                              void* d_out, int out_size, void* d_ws, size_t ws_size,
                              hipStream_t stream) {
    const float* feat   = (const float*)d_in[0];
    const float* Wh     = (const float*)d_in[1];
    const float* Wt     = (const float*)d_in[2];
    const float* We     = (const float*)d_in[3];
    const float* attn_p = (const float*)d_in[4];
    const float* g_head = (const float*)d_in[5];
    const float* g_tail = (const float*)d_in[6];
    const float* ln1_g  = (const float*)d_in[7];
    const float* ln1_b  = (const float*)d_in[8];
    const float* ln2_g  = (const float*)d_in[9];
    const float* ln2_b  = (const float*)d_in[10];
    const float* W1     = (const float*)d_in[11];
    const float* b1     = (const float*)d_in[12];
    const float* W2     = (const float*)d_in[13];
    const float* b2     = (const float*)d_in[14];
    const int*   src    = (const int*)d_in[15];
    // d_in[16] = dst: structurally repeat(arange(N), DEG) — exploited, not read

    float* ws  = (float*)d_ws;
    float* h   = ws;                 // [N,128]  (reused later as x)
    float* fh  = ws + 5120000;       // [N,128]
    float* ftl = ws + 10240000;      // [N,128]
    float* fe  = ws + 15360000;      // [N,128]
    float* gh  = ws + 20480000;      // [N,8]
    float* gt  = ws + 20800000;      // [N,8]
    float* av  = ws + 21120000;      // [E,8]
    float* f0  = ws + 26240000;      // [N,128]
    float* f1  = ws + 31360000;      // [N,128]
    float* x   = h;                  // reuse (h dead after projections)
    float* hidden = fh;              // [N,512] overlays fh/ftl/fe/gh/gt (dead by FFN)
    float* rst = (float*)d_out;      // rst lives in d_out; final GEMM adds it in-place

    dim3 b256(256);
    int nodeBlocks  = (N_NODES * 64) / 256;  // 10000 (wave-per-node kernels)
    int nodeBlocks4 = (N_NODES + 3) / 4;     // hop kernel: 4 nodes/block

    ln_kernel<<<nodeBlocks, b256, 0, stream>>>(feat, ln1_g, ln1_b, h, N_NODES);

    dim3 gproj(N_NODES / 64, 6);
    proj3_gemm<<<gproj, b256, 0, stream>>>(h, Wh, Wt, We, fh, ftl, fe, N_NODES);

    gates_kernel<<<(N_NODES * NH) / 256, b256, 0, stream>>>(fh, ftl, g_head, g_tail, gh, gt, N_NODES * NH);
    attn_kernel<<<nodeBlocks, b256, 0, stream>>>(fh, ftl, gh, gt, attn_p, src, av, N_NODES);

    hop_kernel<<<nodeBlocks4, b256, 0, stream>>>(fe, fe, av, src, f0, N_NODES);
    hop_kernel<<<nodeBlocks4, b256, 0, stream>>>(f0, fe, av, src, f1, N_NODES);
    hop_kernel<<<nodeBlocks4, b256, 0, stream>>>(f1, fe, av, src, f0, N_NODES);
    hop_kernel<<<nodeBlocks4, b256, 0, stream>>>(f0, fe, av, src, f1, N_NODES);
    hop_kernel<<<nodeBlocks4, b256, 0, stream>>>(f1, fe, av, src, f0, N_NODES);

    add_ln_kernel<<<nodeBlocks, b256, 0, stream>>>(f0, feat, ln2_g, ln2_b, rst, x, N_NODES);

    dim3 gff1(N_NODES / 64, FFDIM / 64);
    gemm_bt<<<gff1, b256, 0, stream>>>(x, W1, hidden, b1, nullptr, 1, N_NODES, FFDIM, DIN);
    dim3 gff2(N_NODES / 64, DIN / 64);
    gemm_bt<<<gff2, b256, 0, stream>>>(hidden, W2, rst, b2, rst, 0, N_NODES, DIN, FFDIM);
}

// Round 3
// 504.031 us; speedup vs baseline: 1.3222x; 1.3222x over previous
//
#include <hip/hip_runtime.h>
#include <math.h>

#define N_NODES 40000
#define DEG 16
#define DIN 128
#define NH 8
#define DH 16
#define FFDIM 512
#define ALPHA 0.15f
#define LNEPS 1e-5f

typedef __attribute__((ext_vector_type(8))) short bf16x8;
typedef __attribute__((ext_vector_type(4))) float f32x4;

__device__ inline unsigned int f2bf(float f) {  // round-to-nearest-even f32->bf16
    unsigned int u = __float_as_uint(f);
    return (u + 0x7fffu + ((u >> 16) & 1u)) >> 16;
}

// ---------------- wave helpers (wave = 64) ----------------
__device__ inline float wave_sum64(float v) {
#pragma unroll
    for (int m = 32; m >= 1; m >>= 1) v += __shfl_xor(v, m, 64);
    return v;
}

// ---------------- weight fp32 -> bf16 conversion (per call; ws is re-poisoned) ----------------
__global__ void cvt_weights(const float* __restrict__ wh, const float* __restrict__ wt,
                            const float* __restrict__ we, const float* __restrict__ w1,
                            const float* __restrict__ w2,
                            short* __restrict__ owh, short* __restrict__ owt,
                            short* __restrict__ owe, short* __restrict__ ow1,
                            short* __restrict__ ow2) {
    int i = blockIdx.x * 256 + threadIdx.x;
    if (i < 16384)       owh[i]          = (short)f2bf(wh[i]);
    else if (i < 32768)  owt[i - 16384]  = (short)f2bf(wt[i - 16384]);
    else if (i < 49152)  owe[i - 32768]  = (short)f2bf(we[i - 32768]);
    else if (i < 114688) ow1[i - 49152]  = (short)f2bf(w1[i - 49152]);
    else if (i < 180224) ow2[i - 114688] = (short)f2bf(w2[i - 114688]);
}

// ---------------- LayerNorm: one wave per node, bf16 out ----------------
__global__ void ln_kernel(const float* __restrict__ in, const float* __restrict__ g,
                          const float* __restrict__ b, short* __restrict__ out, int n) {
    int wid  = (blockIdx.x * blockDim.x + threadIdx.x) >> 6;
    int lane = threadIdx.x & 63;
    if (wid >= n) return;
    float2 v = *(const float2*)(in + (size_t)wid * DIN + lane * 2);
    float mean = wave_sum64(v.x + v.y) * (1.0f / DIN);
    float dx = v.x - mean, dy = v.y - mean;
    float var = wave_sum64(dx * dx + dy * dy) * (1.0f / DIN);
    float rstd = rsqrtf(var + LNEPS);
    float2 gg = *(const float2*)(g + lane * 2);
    float2 bb = *(const float2*)(b + lane * 2);
    float o0 = dx * rstd * gg.x + bb.x, o1 = dy * rstd * gg.y + bb.y;
    unsigned int pack = f2bf(o0) | (f2bf(o1) << 16);
    *(unsigned int*)(out + (size_t)wid * DIN + lane * 2) = pack;
}

// rst = f + feat (fp32, to d_out), x = LN(rst) in bf16
__global__ void add_ln_kernel(const float* __restrict__ f, const float* __restrict__ feat,
                              const float* __restrict__ g, const float* __restrict__ b,
                              float* __restrict__ rst, short* __restrict__ x, int n) {
    int wid  = (blockIdx.x * blockDim.x + threadIdx.x) >> 6;
    int lane = threadIdx.x & 63;
    if (wid >= n) return;
    float2 va = *(const float2*)(f + (size_t)wid * DIN + lane * 2);
    float2 vb = *(const float2*)(feat + (size_t)wid * DIN + lane * 2);
    float2 r = { va.x + vb.x, va.y + vb.y };
    *(float2*)(rst + (size_t)wid * DIN + lane * 2) = r;
    float mean = wave_sum64(r.x + r.y) * (1.0f / DIN);
    float dx = r.x - mean, dy = r.y - mean;
    float var = wave_sum64(dx * dx + dy * dy) * (1.0f / DIN);
    float rstd = rsqrtf(var + LNEPS);
    float2 gg = *(const float2*)(g + lane * 2);
    float2 bb = *(const float2*)(b + lane * 2);
    float o0 = dx * rstd * gg.x + bb.x, o1 = dy * rstd * gg.y + bb.y;
    unsigned int pack = f2bf(o0) | (f2bf(o1) << 16);
    *(unsigned int*)(x + (size_t)wid * DIN + lane * 2) = pack;
}

// ---------------- bf16 MFMA GEMM: C = act(A @ B^T + bias) [+ res] ----------------
// A[M,K] bf16 row-major, B[N,K] bf16 row-major (i.e. B^T sense). BM=64, BN=128, BK=64.
// 256 threads = 4 waves (2x2), per-wave 32x64 = acc[2][4] frags of 16x16x32.
// LDS XOR-swizzle: slot = row*8 + (kb ^ (row&7)) -> conflict-free b128 write+read.
__global__ __launch_bounds__(256) void mfma_gemm(
        const short* __restrict__ A, const short* __restrict__ B,
        int M, int N, int K,
        const float* __restrict__ bias, const float* __restrict__ res, int relu,
        float* __restrict__ Cf, short* __restrict__ Cb) {
    __shared__ __align__(16) short Al[64 * 64];
    __shared__ __align__(16) short Bl[128 * 64];
    const int t  = threadIdx.x;
    const int bm = blockIdx.x * 64;
    const int bn = blockIdx.y * 128;
    const int w = t >> 6, lane = t & 63;
    const int wr = w >> 1, wc = w & 1;
    const int l15 = lane & 15, l4 = lane >> 4;
    f32x4 acc[2][4] = {};
    for (int k0 = 0; k0 < K; k0 += 64) {
        __syncthreads();
#pragma unroll
        for (int q = 0; q < 2; ++q) {        // stage A: 64 rows x 8 chunks
            int c = t + q * 256;
            int r = c >> 3, kb = c & 7;
            bf16x8 v = *(const bf16x8*)(A + (size_t)(bm + r) * K + k0 + kb * 8);
            *(bf16x8*)(Al + (r * 8 + (kb ^ (r & 7))) * 8) = v;
        }
#pragma unroll
        for (int q = 0; q < 4; ++q) {        // stage B: 128 rows x 8 chunks
            int c = t + q * 256;
            int r = c >> 3, kb = c & 7;
            bf16x8 v = *(const bf16x8*)(B + (size_t)(bn + r) * K + k0 + kb * 8);
            *(bf16x8*)(Bl + (r * 8 + (kb ^ (r & 7))) * 8) = v;
        }
        __syncthreads();
#pragma unroll
        for (int kc = 0; kc < 2; ++kc) {
            bf16x8 af[2], bfr[4];
#pragma unroll
            for (int mf = 0; mf < 2; ++mf) {
                int row = wr * 32 + mf * 16 + l15;
                int kb = kc * 4 + l4;
                af[mf] = *(const bf16x8*)(Al + (row * 8 + (kb ^ (row & 7))) * 8);
            }
#pragma unroll
            for (int nf = 0; nf < 4; ++nf) {
                int row = wc * 64 + nf * 16 + l15;
                int kb = kc * 4 + l4;
                bfr[nf] = *(const bf16x8*)(Bl + (row * 8 + (kb ^ (row & 7))) * 8);
            }
#pragma unroll
            for (int mf = 0; mf < 2; ++mf)
#pragma unroll
                for (int nf = 0; nf < 4; ++nf)
                    acc[mf][nf] = __builtin_amdgcn_mfma_f32_16x16x32_bf16(
                        af[mf], bfr[nf], acc[mf][nf], 0, 0, 0);
        }
    }
    // epilogue: C/D layout col=lane&15, row=(lane>>4)*4+reg  [HW-verified]
#pragma unroll
    for (int mf = 0; mf < 2; ++mf) {
#pragma unroll
        for (int nf = 0; nf < 4; ++nf) {
            int gcol = bn + wc * 64 + nf * 16 + l15;
            float bv = bias ? bias[gcol] : 0.f;
#pragma unroll
            for (int r = 0; r < 4; ++r) {
                int grow = bm + wr * 32 + mf * 16 + l4 * 4 + r;
                float v = acc[mf][nf][r] + bv;
                if (relu) v = fmaxf(v, 0.f);
                size_t off = (size_t)grow * N + gcol;
                if (res) v += res[off];
                if (Cb) Cb[off] = (short)f2bf(v);
                else    Cf[off] = v;
            }
        }
    }
}

// ---------------- gate scores gh/gt: thread per (node, head) ----------------
__global__ void gates_kernel(const float* __restrict__ fh, const float* __restrict__ ftl,
                             const float* __restrict__ g_head, const float* __restrict__ g_tail,
                             float* __restrict__ gh, float* __restrict__ gt, int total) {
    int t = blockIdx.x * blockDim.x + threadIdx.x;
    if (t >= total) return;
    int i = t >> 3, h = t & 7;
    const float4* fp = (const float4*)(fh + (size_t)i * DIN + h * DH);
    const float4* gp = (const float4*)(g_head + h * DH);
    const float4* fq = (const float4*)(ftl + (size_t)i * DIN + h * DH);
    const float4* gq = (const float4*)(g_tail + h * DH);
    float s1 = 0.f, s2 = 0.f;
#pragma unroll
    for (int q = 0; q < 4; ++q) {
        float4 a = fp[q], b = gp[q];
        s1 += a.x * b.x + a.y * b.y + a.z * b.z + a.w * b.w;
        float4 c = fq[q], d = gq[q];
        s2 += c.x * d.x + c.y * d.y + c.z * d.z + c.w * d.w;
    }
    gh[t] = s1;
    gt[t] = s2;
}

// ---------------- edge attention + softmax: one wave per dst node ----------------
__global__ void attn_kernel(const float* __restrict__ fh, const float* __restrict__ ftl,
                            const float* __restrict__ ghv, const float* __restrict__ gtv,
                            const float* __restrict__ attn_p, const int* __restrict__ src,
                            float* __restrict__ av, int n) {
    int wid  = (blockIdx.x * blockDim.x + threadIdx.x) >> 6;
    int lane = threadIdx.x & 63;
    if (wid >= n) return;
    int e  = lane & 15;
    int h0 = lane >> 4;
    int s = src[(size_t)wid * DEG + e];
    const float4* fhs = (const float4*)(fh + (size_t)s * DIN);
    const float4* fti = (const float4*)(ftl + (size_t)wid * DIN);
    const float4* ap  = (const float4*)attn_p;
    float v0 = 0.f, v1 = 0.f;
#pragma unroll
    for (int q = 0; q < 4; ++q) {
        float4 xa = fhs[h0 * 4 + q], xb = fti[h0 * 4 + q], xc = ap[h0 * 4 + q];
        v0 += xa.x * xb.x * xc.x + xa.y * xb.y * xc.y + xa.z * xb.z * xc.z + xa.w * xb.w * xc.w;
        float4 ya = fhs[(h0 + 4) * 4 + q], yb = fti[(h0 + 4) * 4 + q], yc = ap[(h0 + 4) * 4 + q];
        v1 += ya.x * yb.x * yc.x + ya.y * yb.y * yc.y + ya.z * yb.z * yc.z + ya.w * yb.w * yc.w;
    }
    const float c = 0.17328679513998632f;  // ln(16)/16  (in_deg == 16 structurally)
    v0 *= c; v1 *= c;
    float m0 = v0, m1 = v1;
#pragma unroll
    for (int msk = 1; msk <= 8; msk <<= 1) {
        m0 = fmaxf(m0, __shfl_xor(m0, msk, 64));
        m1 = fmaxf(m1, __shfl_xor(m1, msk, 64));
    }
    float gate0 = 1.f / (1.f + expf(-(ghv[(size_t)s * NH + h0]     + gtv[(size_t)wid * NH + h0])));
    float gate1 = 1.f / (1.f + expf(-(ghv[(size_t)s * NH + h0 + 4] + gtv[(size_t)wid * NH + h0 + 4])));
    float t0 = expf(v0 - m0) * gate0;
    float t1 = expf(v1 - m1) * gate1;
    float s0 = t0, s1 = t1;
#pragma unroll
    for (int msk = 1; msk <= 8; msk <<= 1) {
        s0 += __shfl_xor(s0, msk, 64);
        s1 += __shfl_xor(s1, msk, 64);
    }
    float* ao = av + ((size_t)wid * DEG + e) * NH;
    ao[h0]     = t0 / s0;
    ao[h0 + 4] = t1 / s1;
}

// ---------------- one PPR hop ----------------
__global__ __launch_bounds__(256) void hop_kernel(
        const float* __restrict__ fin, const float* __restrict__ fe,
        const float* __restrict__ av, const int* __restrict__ src,
        float* __restrict__ fout, int n) {
    __shared__ int sidx[4 * DEG];
    int wv   = threadIdx.x >> 6;
    int lane = threadIdx.x & 63;
    int wid  = blockIdx.x * 4 + wv;
    if (threadIdx.x < 4 * DEG) {
        int node = blockIdx.x * 4 + (threadIdx.x >> 4);
        sidx[threadIdx.x] = (node < n) ? src[(size_t)node * DEG + (threadIdx.x & 15)] : 0;
    }
    __syncthreads();
    if (wid >= n) return;
    int h = lane >> 3;
    const float* ae = av + (size_t)wid * DEG * NH;
    const int* se = &sidx[wv * DEG];
    float ax = 0.f, ay = 0.f;
#pragma unroll
    for (int e = 0; e < DEG; ++e) {
        int s = se[e];
        float w = ae[e * NH + h];
        float2 fv = *(const float2*)(fin + (size_t)s * DIN + lane * 2);
        ax += w * fv.x; ay += w * fv.y;
    }
    float2 fev = *(const float2*)(fe + (size_t)wid * DIN + lane * 2);
    float2 o = { (1.f - ALPHA) * ax + ALPHA * fev.x, (1.f - ALPHA) * ay + ALPHA * fev.y };
    *(float2*)(fout + (size_t)wid * DIN + lane * 2) = o;
}

extern "C" void kernel_launch(void* const* d_in, const int* in_sizes, int n_in,
                              void* d_out, int out_size, void* d_ws, size_t ws_size,
                              hipStream_t stream) {
    const float* feat   = (const float*)d_in[0];
    const float* Wh     = (const float*)d_in[1];
    const float* Wt     = (const float*)d_in[2];
    const float* We     = (const float*)d_in[3];
    const float* attn_p = (const float*)d_in[4];
    const float* g_head = (const float*)d_in[5];
    const float* g_tail = (const float*)d_in[6];
    const float* ln1_g  = (const float*)d_in[7];
    const float* ln1_b  = (const float*)d_in[8];
    const float* ln2_g  = (const float*)d_in[9];
    const float* ln2_b  = (const float*)d_in[10];
    const float* W1     = (const float*)d_in[11];
    const float* b1     = (const float*)d_in[12];
    const float* W2     = (const float*)d_in[13];
    const float* b2     = (const float*)d_in[14];
    const int*   src    = (const int*)d_in[15];
    // d_in[16] = dst: structurally repeat(arange(N), DEG) — exploited, not read

    float* ws  = (float*)d_ws;
    float* fh  = ws;                 // [N,128] fp32
    float* ftl = ws + 5120000;       // [N,128]
    float* fe  = ws + 10240000;      // [N,128]
    float* gh  = ws + 15360000;      // [N,8]
    float* gt  = ws + 15680000;      // [N,8]
    float* av  = ws + 16000000;      // [E,8]   ends 21.12M
    float* f0  = ws + 21120000;      // [N,128] ends 26.24M
    float* f1  = ws + 26240000;      // [N,128] ends 31.36M
    // bf16 buffers (lifetime-disjoint overlays):
    short* h_bf    = (short*)(ws + 31360000);  // [N,128] bf16; dead before f1-extension below
    short* x_bf    = (short*)(ws + 33920000);  // [N,128] bf16; written after hops
    short* hidden  = (short*)ws;               // [N,512] bf16 overlays fh/ftl (dead by FFN)
    short* wb      = (short*)(ws + 36480000);  // weights bf16: 180224 shorts
    short* wh_bf = wb, *wt_bf = wb + 16384, *we_bf = wb + 32768;
    short* w1_bf = wb + 49152, *w2_bf = wb + 114688;
    float* rst = (float*)d_out;      // rst lives in d_out; FFN2 adds it in-place

    dim3 b256(256);
    int nodeBlocks  = (N_NODES * 64) / 256;  // 10000
    int nodeBlocks4 = (N_NODES + 3) / 4;

    cvt_weights<<<704, b256, 0, stream>>>(Wh, Wt, We, W1, W2, wh_bf, wt_bf, we_bf, w1_bf, w2_bf);
    ln_kernel<<<nodeBlocks, b256, 0, stream>>>(feat, ln1_g, ln1_b, h_bf, N_NODES);

    dim3 gp(N_NODES / 64, 1);
    mfma_gemm<<<gp, b256, 0, stream>>>(h_bf, wh_bf, N_NODES, DIN, DIN, nullptr, nullptr, 0, fh,  nullptr);
    mfma_gemm<<<gp, b256, 0, stream>>>(h_bf, wt_bf, N_NODES, DIN, DIN, nullptr, nullptr, 0, ftl, nullptr);
    mfma_gemm<<<gp, b256, 0, stream>>>(h_bf, we_bf, N_NODES, DIN, DIN, nullptr, nullptr, 0, fe,  nullptr);

    gates_kernel<<<(N_NODES * NH) / 256, b256, 0, stream>>>(fh, ftl, g_head, g_tail, gh, gt, N_NODES * NH);
    attn_kernel<<<nodeBlocks, b256, 0, stream>>>(fh, ftl, gh, gt, attn_p, src, av, N_NODES);

    hop_kernel<<<nodeBlocks4, b256, 0, stream>>>(fe, fe, av, src, f0, N_NODES);
    hop_kernel<<<nodeBlocks4, b256, 0, stream>>>(f0, fe, av, src, f1, N_NODES);
    hop_kernel<<<nodeBlocks4, b256, 0, stream>>>(f1, fe, av, src, f0, N_NODES);
    hop_kernel<<<nodeBlocks4, b256, 0, stream>>>(f0, fe, av, src, f1, N_NODES);
    hop_kernel<<<nodeBlocks4, b256, 0, stream>>>(f1, fe, av, src, f0, N_NODES);

    add_ln_kernel<<<nodeBlocks, b256, 0, stream>>>(f0, feat, ln2_g, ln2_b, rst, x_bf, N_NODES);

    dim3 gff1(N_NODES / 64, FFDIM / 128);
    mfma_gemm<<<gff1, b256, 0, stream>>>(x_bf, w1_bf, N_NODES, FFDIM, DIN, b1, nullptr, 1, nullptr, hidden);
    dim3 gff2(N_NODES / 64, 1);
    mfma_gemm<<<gff2, b256, 0, stream>>>(hidden, w2_bf, N_NODES, DIN, FFDIM, b2, rst, 0, rst, nullptr);
}

// Round 5
// 373.858 us; speedup vs baseline: 1.7826x; 1.3482x over previous
//
#include <hip/hip_runtime.h>
#include <math.h>

#define N_NODES 40000
#define DEG 16
#define DIN 128
#define NH 8
#define DH 16
#define FFDIM 512
#define ALPHA 0.15f
#define LNEPS 1e-5f

typedef __attribute__((ext_vector_type(8))) short bf16x8;
typedef __attribute__((ext_vector_type(4))) float f32x4;
typedef __attribute__((ext_vector_type(4))) unsigned int u32x4;

__device__ inline unsigned int f2bf(float f) {  // round-to-nearest-even f32->bf16
    unsigned int u = __float_as_uint(f);
    return (u + 0x7fffu + ((u >> 16) & 1u)) >> 16;
}
__device__ inline float bflo(unsigned u) { return __uint_as_float(u << 16); }
__device__ inline float bfhi(unsigned u) { return __uint_as_float(u & 0xffff0000u); }

// sum over 8 bf16 pairs: f*t*w (attention logits)
__device__ inline float dot8(u32x4 uf, u32x4 ut, const float* __restrict__ ap) {
    float s = 0.f;
#pragma unroll
    for (int k = 0; k < 4; ++k) {
        s += bflo(uf[k]) * bflo(ut[k]) * ap[2 * k]
           + bfhi(uf[k]) * bfhi(ut[k]) * ap[2 * k + 1];
    }
    return s;
}
// sum over 8 bf16: u*w (gate scores)
__device__ inline float dot8w(u32x4 u, const float* __restrict__ w) {
    float s = 0.f;
#pragma unroll
    for (int k = 0; k < 4; ++k) {
        s += bflo(u[k]) * w[2 * k] + bfhi(u[k]) * w[2 * k + 1];
    }
    return s;
}

// ---------------- wave helpers (wave = 64) ----------------
__device__ inline float wave_sum64(float v) {
#pragma unroll
    for (int m = 32; m >= 1; m >>= 1) v += __shfl_xor(v, m, 64);
    return v;
}

// ---------------- weight fp32 -> bf16 conversion ----------------
__global__ void cvt_weights(const float* __restrict__ wh, const float* __restrict__ wt,
                            const float* __restrict__ we, const float* __restrict__ w1,
                            const float* __restrict__ w2,
                            short* __restrict__ owh, short* __restrict__ owt,
                            short* __restrict__ owe, short* __restrict__ ow1,
                            short* __restrict__ ow2) {
    int i = blockIdx.x * 256 + threadIdx.x;
    if (i < 16384)       owh[i]          = (short)f2bf(wh[i]);
    else if (i < 32768)  owt[i - 16384]  = (short)f2bf(wt[i - 16384]);
    else if (i < 49152)  owe[i - 32768]  = (short)f2bf(we[i - 32768]);
    else if (i < 114688) ow1[i - 49152]  = (short)f2bf(w1[i - 49152]);
    else if (i < 180224) ow2[i - 114688] = (short)f2bf(w2[i - 114688]);
}

// ---------------- LayerNorm: one wave per node, bf16 out ----------------
__global__ void ln_kernel(const float* __restrict__ in, const float* __restrict__ g,
                          const float* __restrict__ b, short* __restrict__ out, int n) {
    int wid  = (blockIdx.x * blockDim.x + threadIdx.x) >> 6;
    int lane = threadIdx.x & 63;
    if (wid >= n) return;
    float2 v = *(const float2*)(in + (size_t)wid * DIN + lane * 2);
    float mean = wave_sum64(v.x + v.y) * (1.0f / DIN);
    float dx = v.x - mean, dy = v.y - mean;
    float var = wave_sum64(dx * dx + dy * dy) * (1.0f / DIN);
    float rstd = rsqrtf(var + LNEPS);
    float2 gg = *(const float2*)(g + lane * 2);
    float2 bb = *(const float2*)(b + lane * 2);
    float o0 = dx * rstd * gg.x + bb.x, o1 = dy * rstd * gg.y + bb.y;
    unsigned int pack = f2bf(o0) | (f2bf(o1) << 16);
    *(unsigned int*)(out + (size_t)wid * DIN + lane * 2) = pack;
}

// rst = f + feat (fp32, to d_out), x = LN(rst) in bf16
__global__ void add_ln_kernel(const float* __restrict__ f, const float* __restrict__ feat,
                              const float* __restrict__ g, const float* __restrict__ b,
                              float* __restrict__ rst, short* __restrict__ x, int n) {
    int wid  = (blockIdx.x * blockDim.x + threadIdx.x) >> 6;
    int lane = threadIdx.x & 63;
    if (wid >= n) return;
    float2 va = *(const float2*)(f + (size_t)wid * DIN + lane * 2);
    float2 vb = *(const float2*)(feat + (size_t)wid * DIN + lane * 2);
    float2 r = { va.x + vb.x, va.y + vb.y };
    *(float2*)(rst + (size_t)wid * DIN + lane * 2) = r;
    float mean = wave_sum64(r.x + r.y) * (1.0f / DIN);
    float dx = r.x - mean, dy = r.y - mean;
    float var = wave_sum64(dx * dx + dy * dy) * (1.0f / DIN);
    float rstd = rsqrtf(var + LNEPS);
    float2 gg = *(const float2*)(g + lane * 2);
    float2 bb = *(const float2*)(b + lane * 2);
    float o0 = dx * rstd * gg.x + bb.x, o1 = dy * rstd * gg.y + bb.y;
    unsigned int pack = f2bf(o0) | (f2bf(o1) << 16);
    *(unsigned int*)(x + (size_t)wid * DIN + lane * 2) = pack;
}

// ---------------- bf16 MFMA GEMM: C = act(A @ B^T + bias) [+ res] ----------------
// Writes Cf (fp32) and/or Cb (bf16) — both if both non-null.
__global__ __launch_bounds__(256) void mfma_gemm(
        const short* __restrict__ A, const short* __restrict__ B,
        int M, int N, int K,
        const float* __restrict__ bias, const float* __restrict__ res, int relu,
        float* __restrict__ Cf, short* __restrict__ Cb) {
    __shared__ __align__(16) short Al[64 * 64];
    __shared__ __align__(16) short Bl[128 * 64];
    const int t  = threadIdx.x;
    const int bm = blockIdx.x * 64;
    const int bn = blockIdx.y * 128;
    const int w = t >> 6, lane = t & 63;
    const int wr = w >> 1, wc = w & 1;
    const int l15 = lane & 15, l4 = lane >> 4;
    f32x4 acc[2][4] = {};
    for (int k0 = 0; k0 < K; k0 += 64) {
        __syncthreads();
#pragma unroll
        for (int q = 0; q < 2; ++q) {
            int c = t + q * 256;
            int r = c >> 3, kb = c & 7;
            bf16x8 v = *(const bf16x8*)(A + (size_t)(bm + r) * K + k0 + kb * 8);
            *(bf16x8*)(Al + (r * 8 + (kb ^ (r & 7))) * 8) = v;
        }
#pragma unroll
        for (int q = 0; q < 4; ++q) {
            int c = t + q * 256;
            int r = c >> 3, kb = c & 7;
            bf16x8 v = *(const bf16x8*)(B + (size_t)(bn + r) * K + k0 + kb * 8);
            *(bf16x8*)(Bl + (r * 8 + (kb ^ (r & 7))) * 8) = v;
        }
        __syncthreads();
#pragma unroll
        for (int kc = 0; kc < 2; ++kc) {
            bf16x8 af[2], bfr[4];
#pragma unroll
            for (int mf = 0; mf < 2; ++mf) {
                int row = wr * 32 + mf * 16 + l15;
                int kb = kc * 4 + l4;
                af[mf] = *(const bf16x8*)(Al + (row * 8 + (kb ^ (row & 7))) * 8);
            }
#pragma unroll
            for (int nf = 0; nf < 4; ++nf) {
                int row = wc * 64 + nf * 16 + l15;
                int kb = kc * 4 + l4;
                bfr[nf] = *(const bf16x8*)(Bl + (row * 8 + (kb ^ (row & 7))) * 8);
            }
#pragma unroll
            for (int mf = 0; mf < 2; ++mf)
#pragma unroll
                for (int nf = 0; nf < 4; ++nf)
                    acc[mf][nf] = __builtin_amdgcn_mfma_f32_16x16x32_bf16(
                        af[mf], bfr[nf], acc[mf][nf], 0, 0, 0);
        }
    }
#pragma unroll
    for (int mf = 0; mf < 2; ++mf) {
#pragma unroll
        for (int nf = 0; nf < 4; ++nf) {
            int gcol = bn + wc * 64 + nf * 16 + l15;
            float bv = bias ? bias[gcol] : 0.f;
#pragma unroll
            for (int r = 0; r < 4; ++r) {
                int grow = bm + wr * 32 + mf * 16 + l4 * 4 + r;
                float v = acc[mf][nf][r] + bv;
                if (relu) v = fmaxf(v, 0.f);
                size_t off = (size_t)grow * N + gcol;
                if (res) v += res[off];
                if (Cb) Cb[off] = (short)f2bf(v);
                if (Cf) Cf[off] = v;
            }
        }
    }
}

// ------- edge attention + softmax + inline gates (bf16 fh/ftl): one wave per dst -------
// Gate dots computed from the fh[s]/ftl[dst] registers already loaded -> no gh/gt tables.
__global__ void attn_kernel(const short* __restrict__ fh, const short* __restrict__ ftl,
                            const float* __restrict__ g_head, const float* __restrict__ g_tail,
                            const float* __restrict__ attn_p, const int* __restrict__ src,
                            float* __restrict__ av, int n) {
    int wid  = (blockIdx.x * blockDim.x + threadIdx.x) >> 6;
    int lane = threadIdx.x & 63;
    if (wid >= n) return;
    int e  = lane & 15;
    int h0 = lane >> 4;
    int s = src[(size_t)wid * DEG + e];
    const short* fr0 = fh  + (size_t)s   * DIN + h0 * DH;
    const short* tr0 = ftl + (size_t)wid * DIN + h0 * DH;
    // head h0 (dims 0..15) and head h0+4 (offset 64 shorts)
    u32x4 f0a = *(const u32x4*)(fr0);
    u32x4 f0b = *(const u32x4*)(fr0 + 8);
    u32x4 t0a = *(const u32x4*)(tr0);
    u32x4 t0b = *(const u32x4*)(tr0 + 8);
    u32x4 f1a = *(const u32x4*)(fr0 + 64);
    u32x4 f1b = *(const u32x4*)(fr0 + 72);
    u32x4 t1a = *(const u32x4*)(tr0 + 64);
    u32x4 t1b = *(const u32x4*)(tr0 + 72);
    const float* ap0 = attn_p + h0 * DH;
    float v0 = dot8(f0a, t0a, ap0) + dot8(f0b, t0b, ap0 + 8);
    float v1 = dot8(f1a, t1a, ap0 + 64) + dot8(f1b, t1b, ap0 + 72);
    const float c = 0.17328679513998632f;  // ln(16)/16  (in_deg == 16 structurally)
    v0 *= c; v1 *= c;
    // gate scores from registers (replaces gates_kernel + gh/gt gathers)
    const float* gh0 = g_head + h0 * DH;
    const float* gt0 = g_tail + h0 * DH;
    float gs0 = dot8w(f0a, gh0) + dot8w(f0b, gh0 + 8)
              + dot8w(t0a, gt0) + dot8w(t0b, gt0 + 8);
    float gs1 = dot8w(f1a, gh0 + 64) + dot8w(f1b, gh0 + 72)
              + dot8w(t1a, gt0 + 64) + dot8w(t1b, gt0 + 72);
    float m0 = v0, m1 = v1;
#pragma unroll
    for (int msk = 1; msk <= 8; msk <<= 1) {
        m0 = fmaxf(m0, __shfl_xor(m0, msk, 64));
        m1 = fmaxf(m1, __shfl_xor(m1, msk, 64));
    }
    float gate0 = 1.f / (1.f + expf(-gs0));
    float gate1 = 1.f / (1.f + expf(-gs1));
    float t0 = expf(v0 - m0) * gate0;
    float t1 = expf(v1 - m1) * gate1;
    float s0 = t0, s1 = t1;
#pragma unroll
    for (int msk = 1; msk <= 8; msk <<= 1) {
        s0 += __shfl_xor(s0, msk, 64);
        s1 += __shfl_xor(s1, msk, 64);
    }
    float* ao = av + ((size_t)wid * DEG + e) * NH;
    ao[h0]     = t0 / s0;
    ao[h0 + 4] = t1 / s1;
}

// ---------------- one PPR hop: bf16 gather, fp32 accumulate, bf16 or fp32 store ----------------
__global__ __launch_bounds__(256) void hop_kernel(
        const short* __restrict__ fin, const float* __restrict__ fe,
        const float* __restrict__ av, const int* __restrict__ src,
        short* __restrict__ fout_b, float* __restrict__ fout_f, int n) {
    __shared__ int sidx[4 * DEG];
    int wv   = threadIdx.x >> 6;
    int lane = threadIdx.x & 63;
    int wid  = blockIdx.x * 4 + wv;
    if (threadIdx.x < 4 * DEG) {
        int node = blockIdx.x * 4 + (threadIdx.x >> 4);
        sidx[threadIdx.x] = (node < n) ? src[(size_t)node * DEG + (threadIdx.x & 15)] : 0;
    }
    __syncthreads();
    if (wid >= n) return;
    int h = lane >> 3;
    const float* ae = av + (size_t)wid * DEG * NH;
    const int* se = &sidx[wv * DEG];
    float ax = 0.f, ay = 0.f;
#pragma unroll
    for (int e = 0; e < DEG; ++e) {
        int s = se[e];
        float w = ae[e * NH + h];
        unsigned u = *(const unsigned*)(fin + (size_t)s * DIN + lane * 2);
        ax += w * bflo(u);
        ay += w * bfhi(u);
    }
    float2 fev = *(const float2*)(fe + (size_t)wid * DIN + lane * 2);
    float ox = (1.f - ALPHA) * ax + ALPHA * fev.x;
    float oy = (1.f - ALPHA) * ay + ALPHA * fev.y;
    if (fout_b) {
        unsigned pack = f2bf(ox) | (f2bf(oy) << 16);
        *(unsigned*)(fout_b + (size_t)wid * DIN + lane * 2) = pack;
    } else {
        float2 o = { ox, oy };
        *(float2*)(fout_f + (size_t)wid * DIN + lane * 2) = o;
    }
}

extern "C" void kernel_launch(void* const* d_in, const int* in_sizes, int n_in,
                              void* d_out, int out_size, void* d_ws, size_t ws_size,
                              hipStream_t stream) {
    const float* feat   = (const float*)d_in[0];
    const float* Wh     = (const float*)d_in[1];
    const float* Wt     = (const float*)d_in[2];
    const float* We     = (const float*)d_in[3];
    const float* attn_p = (const float*)d_in[4];
    const float* g_head = (const float*)d_in[5];
    const float* g_tail = (const float*)d_in[6];
    const float* ln1_g  = (const float*)d_in[7];
    const float* ln1_b  = (const float*)d_in[8];
    const float* ln2_g  = (const float*)d_in[9];
    const float* ln2_b  = (const float*)d_in[10];
    const float* W1     = (const float*)d_in[11];
    const float* b1     = (const float*)d_in[12];
    const float* W2     = (const float*)d_in[13];
    const float* b2     = (const float*)d_in[14];
    const int*   src    = (const int*)d_in[15];
    // d_in[16] = dst: structurally repeat(arange(N), DEG) — exploited, not read

    float* ws = (float*)d_ws;
    // fp32 buffers
    float* fe   = ws;                  // [N,128]             0 .. 5.12M
    float* av   = ws + 5120000;        // [E,8]               .. 10.24M
    // bf16 buffers (float-offset base, cast)
    short* h_bf   = (short*)(ws + 10880000);  // [N,128]b .. 13.44M
    short* fh_bf  = (short*)(ws + 13440000);  // [N,128]b .. 16.00M
    short* ftl_bf = (short*)(ws + 16000000);  // [N,128]b .. 18.56M
    short* fe_bf  = (short*)(ws + 18560000);  // [N,128]b .. 21.12M
    short* f0_bf  = (short*)(ws + 21120000);  // [N,128]b .. 23.68M
    short* f1_bf  = (short*)(ws + 23680000);  // [N,128]b .. 26.24M
    float* ffin   = ws + 26240000;            // [N,128]f .. 31.36M (hop5 out)
    short* x_bf   = (short*)(ws + 31360000);  // [N,128]b .. 33.92M
    short* hidden = (short*)ws;               // [N,512]b overlays fe+av (dead by FFN)
    short* wb     = (short*)(ws + 33920000);  // weights bf16: 180224 shorts
    short* wh_bf = wb, *wt_bf = wb + 16384, *we_bf = wb + 32768;
    short* w1_bf = wb + 49152, *w2_bf = wb + 114688;
    float* rst = (float*)d_out;

    dim3 b256(256);
    int nodeBlocks  = (N_NODES * 64) / 256;  // 10000
    int nodeBlocks4 = (N_NODES + 3) / 4;

    cvt_weights<<<704, b256, 0, stream>>>(Wh, Wt, We, W1, W2, wh_bf, wt_bf, we_bf, w1_bf, w2_bf);
    ln_kernel<<<nodeBlocks, b256, 0, stream>>>(feat, ln1_g, ln1_b, h_bf, N_NODES);

    dim3 gp(N_NODES / 64, 1);
    mfma_gemm<<<gp, b256, 0, stream>>>(h_bf, wh_bf, N_NODES, DIN, DIN, nullptr, nullptr, 0, nullptr, fh_bf);
    mfma_gemm<<<gp, b256, 0, stream>>>(h_bf, wt_bf, N_NODES, DIN, DIN, nullptr, nullptr, 0, nullptr, ftl_bf);
    mfma_gemm<<<gp, b256, 0, stream>>>(h_bf, we_bf, N_NODES, DIN, DIN, nullptr, nullptr, 0, fe, fe_bf);

    attn_kernel<<<nodeBlocks, b256, 0, stream>>>(fh_bf, ftl_bf, g_head, g_tail, attn_p, src, av, N_NODES);

    hop_kernel<<<nodeBlocks4, b256, 0, stream>>>(fe_bf, fe, av, src, f0_bf, nullptr, N_NODES);
    hop_kernel<<<nodeBlocks4, b256, 0, stream>>>(f0_bf, fe, av, src, f1_bf, nullptr, N_NODES);
    hop_kernel<<<nodeBlocks4, b256, 0, stream>>>(f1_bf, fe, av, src, f0_bf, nullptr, N_NODES);
    hop_kernel<<<nodeBlocks4, b256, 0, stream>>>(f0_bf, fe, av, src, f1_bf, nullptr, N_NODES);
    hop_kernel<<<nodeBlocks4, b256, 0, stream>>>(f1_bf, fe, av, src, nullptr, ffin, N_NODES);

    add_ln_kernel<<<nodeBlocks, b256, 0, stream>>>(ffin, feat, ln2_g, ln2_b, rst, x_bf, N_NODES);

    dim3 gff1(N_NODES / 64, FFDIM / 128);
    mfma_gemm<<<gff1, b256, 0, stream>>>(x_bf, w1_bf, N_NODES, FFDIM, DIN, b1, nullptr, 1, nullptr, hidden);
    dim3 gff2(N_NODES / 64, 1);
    mfma_gemm<<<gff2, b256, 0, stream>>>(hidden, w2_bf, N_NODES, DIN, FFDIM, b2, rst, 0, rst, nullptr);
}

// Round 6
// 367.680 us; speedup vs baseline: 1.8126x; 1.0168x over previous
//
#include <hip/hip_runtime.h>
#include <math.h>

#define N_NODES 40000
#define DEG 16
#define DIN 128
#define NH 8
#define DH 16
#define FFDIM 512
#define ALPHA 0.15f
#define LNEPS 1e-5f

typedef __attribute__((ext_vector_type(8))) short bf16x8;
typedef __attribute__((ext_vector_type(4))) float f32x4;
typedef __attribute__((ext_vector_type(4))) unsigned int u32x4;

__device__ inline unsigned int f2bf(float f) {  // round-to-nearest-even f32->bf16
    unsigned int u = __float_as_uint(f);
    return (u + 0x7fffu + ((u >> 16) & 1u)) >> 16;
}
__device__ inline float bflo(unsigned u) { return __uint_as_float(u << 16); }
__device__ inline float bfhi(unsigned u) { return __uint_as_float(u & 0xffff0000u); }

// sum over 8 bf16 pairs: f*t*w (attention logits)
__device__ inline float dot8(u32x4 uf, u32x4 ut, const float* __restrict__ ap) {
    float s = 0.f;
#pragma unroll
    for (int k = 0; k < 4; ++k) {
        s += bflo(uf[k]) * bflo(ut[k]) * ap[2 * k]
           + bfhi(uf[k]) * bfhi(ut[k]) * ap[2 * k + 1];
    }
    return s;
}

// ---------------- wave helpers (wave = 64) ----------------
__device__ inline float wave_sum64(float v) {
#pragma unroll
    for (int m = 32; m >= 1; m >>= 1) v += __shfl_xor(v, m, 64);
    return v;
}

// ---------------- weight fp32 -> bf16 conversion ----------------
__global__ void cvt_weights(const float* __restrict__ wh, const float* __restrict__ wt,
                            const float* __restrict__ we, const float* __restrict__ w1,
                            const float* __restrict__ w2,
                            short* __restrict__ owh, short* __restrict__ owt,
                            short* __restrict__ owe, short* __restrict__ ow1,
                            short* __restrict__ ow2) {
    int i = blockIdx.x * 256 + threadIdx.x;
    if (i < 16384)       owh[i]          = (short)f2bf(wh[i]);
    else if (i < 32768)  owt[i - 16384]  = (short)f2bf(wt[i - 16384]);
    else if (i < 49152)  owe[i - 32768]  = (short)f2bf(we[i - 32768]);
    else if (i < 114688) ow1[i - 49152]  = (short)f2bf(w1[i - 49152]);
    else if (i < 180224) ow2[i - 114688] = (short)f2bf(w2[i - 114688]);
}

// ---------------- LayerNorm: one wave per node, bf16 out ----------------
__global__ void ln_kernel(const float* __restrict__ in, const float* __restrict__ g,
                          const float* __restrict__ b, short* __restrict__ out, int n) {
    int wid  = (blockIdx.x * blockDim.x + threadIdx.x) >> 6;
    int lane = threadIdx.x & 63;
    if (wid >= n) return;
    float2 v = *(const float2*)(in + (size_t)wid * DIN + lane * 2);
    float mean = wave_sum64(v.x + v.y) * (1.0f / DIN);
    float dx = v.x - mean, dy = v.y - mean;
    float var = wave_sum64(dx * dx + dy * dy) * (1.0f / DIN);
    float rstd = rsqrtf(var + LNEPS);
    float2 gg = *(const float2*)(g + lane * 2);
    float2 bb = *(const float2*)(b + lane * 2);
    float o0 = dx * rstd * gg.x + bb.x, o1 = dy * rstd * gg.y + bb.y;
    unsigned int pack = f2bf(o0) | (f2bf(o1) << 16);
    *(unsigned int*)(out + (size_t)wid * DIN + lane * 2) = pack;
}

// rst = f + feat (fp32, to d_out), x = LN(rst) in bf16
__global__ void add_ln_kernel(const float* __restrict__ f, const float* __restrict__ feat,
                              const float* __restrict__ g, const float* __restrict__ b,
                              float* __restrict__ rst, short* __restrict__ x, int n) {
    int wid  = (blockIdx.x * blockDim.x + threadIdx.x) >> 6;
    int lane = threadIdx.x & 63;
    if (wid >= n) return;
    float2 va = *(const float2*)(f + (size_t)wid * DIN + lane * 2);
    float2 vb = *(const float2*)(feat + (size_t)wid * DIN + lane * 2);
    float2 r = { va.x + vb.x, va.y + vb.y };
    *(float2*)(rst + (size_t)wid * DIN + lane * 2) = r;
    float mean = wave_sum64(r.x + r.y) * (1.0f / DIN);
    float dx = r.x - mean, dy = r.y - mean;
    float var = wave_sum64(dx * dx + dy * dy) * (1.0f / DIN);
    float rstd = rsqrtf(var + LNEPS);
    float2 gg = *(const float2*)(g + lane * 2);
    float2 bb = *(const float2*)(b + lane * 2);
    float o0 = dx * rstd * gg.x + bb.x, o1 = dy * rstd * gg.y + bb.y;
    unsigned int pack = f2bf(o0) | (f2bf(o1) << 16);
    *(unsigned int*)(x + (size_t)wid * DIN + lane * 2) = pack;
}

// ---------------- bf16 MFMA GEMM: C = act(A @ B^T + bias) [+ res] ----------------
__global__ __launch_bounds__(256) void mfma_gemm(
        const short* __restrict__ A, const short* __restrict__ B,
        int M, int N, int K,
        const float* __restrict__ bias, const float* __restrict__ res, int relu,
        float* __restrict__ Cf, short* __restrict__ Cb) {
    __shared__ __align__(16) short Al[64 * 64];
    __shared__ __align__(16) short Bl[128 * 64];
    const int t  = threadIdx.x;
    const int bm = blockIdx.x * 64;
    const int bn = blockIdx.y * 128;
    const int w = t >> 6, lane = t & 63;
    const int wr = w >> 1, wc = w & 1;
    const int l15 = lane & 15, l4 = lane >> 4;
    f32x4 acc[2][4] = {};
    for (int k0 = 0; k0 < K; k0 += 64) {
        __syncthreads();
#pragma unroll
        for (int q = 0; q < 2; ++q) {
            int c = t + q * 256;
            int r = c >> 3, kb = c & 7;
            bf16x8 v = *(const bf16x8*)(A + (size_t)(bm + r) * K + k0 + kb * 8);
            *(bf16x8*)(Al + (r * 8 + (kb ^ (r & 7))) * 8) = v;
        }
#pragma unroll
        for (int q = 0; q < 4; ++q) {
            int c = t + q * 256;
            int r = c >> 3, kb = c & 7;
            bf16x8 v = *(const bf16x8*)(B + (size_t)(bn + r) * K + k0 + kb * 8);
            *(bf16x8*)(Bl + (r * 8 + (kb ^ (r & 7))) * 8) = v;
        }
        __syncthreads();
#pragma unroll
        for (int kc = 0; kc < 2; ++kc) {
            bf16x8 af[2], bfr[4];
#pragma unroll
            for (int mf = 0; mf < 2; ++mf) {
                int row = wr * 32 + mf * 16 + l15;
                int kb = kc * 4 + l4;
                af[mf] = *(const bf16x8*)(Al + (row * 8 + (kb ^ (row & 7))) * 8);
            }
#pragma unroll
            for (int nf = 0; nf < 4; ++nf) {
                int row = wc * 64 + nf * 16 + l15;
                int kb = kc * 4 + l4;
                bfr[nf] = *(const bf16x8*)(Bl + (row * 8 + (kb ^ (row & 7))) * 8);
            }
#pragma unroll
            for (int mf = 0; mf < 2; ++mf)
#pragma unroll
                for (int nf = 0; nf < 4; ++nf)
                    acc[mf][nf] = __builtin_amdgcn_mfma_f32_16x16x32_bf16(
                        af[mf], bfr[nf], acc[mf][nf], 0, 0, 0);
        }
    }
#pragma unroll
    for (int mf = 0; mf < 2; ++mf) {
#pragma unroll
        for (int nf = 0; nf < 4; ++nf) {
            int gcol = bn + wc * 64 + nf * 16 + l15;
            float bv = bias ? bias[gcol] : 0.f;
#pragma unroll
            for (int r = 0; r < 4; ++r) {
                int grow = bm + wr * 32 + mf * 16 + l4 * 4 + r;
                float v = acc[mf][nf][r] + bv;
                if (relu) v = fmaxf(v, 0.f);
                size_t off = (size_t)grow * N + gcol;
                if (res) v += res[off];
                if (Cb) Cb[off] = (short)f2bf(v);
                if (Cf) Cf[off] = v;
            }
        }
    }
}

// ---------------- gate scores gh/gt (bf16 inputs): thread per (node, head) ----------------
__global__ void gates_kernel(const short* __restrict__ fh, const short* __restrict__ ftl,
                             const float* __restrict__ g_head, const float* __restrict__ g_tail,
                             float* __restrict__ gh, float* __restrict__ gt, int total) {
    int t = blockIdx.x * blockDim.x + threadIdx.x;
    if (t >= total) return;
    int i = t >> 3, h = t & 7;
    const short* fp = fh + (size_t)i * DIN + h * DH;
    const short* fq = ftl + (size_t)i * DIN + h * DH;
    const float* gp = g_head + h * DH;
    const float* gq = g_tail + h * DH;
    float s1 = 0.f, s2 = 0.f;
#pragma unroll
    for (int d = 0; d < DH; d += 2) {
        unsigned a = *(const unsigned*)(fp + d);
        unsigned b = *(const unsigned*)(fq + d);
        s1 += bflo(a) * gp[d] + bfhi(a) * gp[d + 1];
        s2 += bflo(b) * gq[d] + bfhi(b) * gq[d + 1];
    }
    gh[t] = s1;
    gt[t] = s2;
}

// ------- edge attention + softmax (bf16 fh/ftl, table gates): one wave per dst -------
__global__ void attn_kernel(const short* __restrict__ fh, const short* __restrict__ ftl,
                            const float* __restrict__ ghv, const float* __restrict__ gtv,
                            const float* __restrict__ attn_p, const int* __restrict__ src,
                            float* __restrict__ av, int n) {
    int wid  = (blockIdx.x * blockDim.x + threadIdx.x) >> 6;
    int lane = threadIdx.x & 63;
    if (wid >= n) return;
    int e  = lane & 15;
    int h0 = lane >> 4;
    int s = src[(size_t)wid * DEG + e];
    const short* fr0 = fh  + (size_t)s   * DIN + h0 * DH;
    const short* tr0 = ftl + (size_t)wid * DIN + h0 * DH;
    u32x4 f0a = *(const u32x4*)(fr0);
    u32x4 f0b = *(const u32x4*)(fr0 + 8);
    u32x4 t0a = *(const u32x4*)(tr0);
    u32x4 t0b = *(const u32x4*)(tr0 + 8);
    u32x4 f1a = *(const u32x4*)(fr0 + 64);
    u32x4 f1b = *(const u32x4*)(fr0 + 72);
    u32x4 t1a = *(const u32x4*)(tr0 + 64);
    u32x4 t1b = *(const u32x4*)(tr0 + 72);
    const float* ap0 = attn_p + h0 * DH;
    float v0 = dot8(f0a, t0a, ap0) + dot8(f0b, t0b, ap0 + 8);
    float v1 = dot8(f1a, t1a, ap0 + 64) + dot8(f1b, t1b, ap0 + 72);
    const float c = 0.17328679513998632f;  // ln(16)/16  (in_deg == 16 structurally)
    v0 *= c; v1 *= c;
    float m0 = v0, m1 = v1;
#pragma unroll
    for (int msk = 1; msk <= 8; msk <<= 1) {
        m0 = fmaxf(m0, __shfl_xor(m0, msk, 64));
        m1 = fmaxf(m1, __shfl_xor(m1, msk, 64));
    }
    float gate0 = 1.f / (1.f + expf(-(ghv[(size_t)s * NH + h0]     + gtv[(size_t)wid * NH + h0])));
    float gate1 = 1.f / (1.f + expf(-(ghv[(size_t)s * NH + h0 + 4] + gtv[(size_t)wid * NH + h0 + 4])));
    float t0 = expf(v0 - m0) * gate0;
    float t1 = expf(v1 - m1) * gate1;
    float s0 = t0, s1 = t1;
#pragma unroll
    for (int msk = 1; msk <= 8; msk <<= 1) {
        s0 += __shfl_xor(s0, msk, 64);
        s1 += __shfl_xor(s1, msk, 64);
    }
    float* ao = av + ((size_t)wid * DEG + e) * NH;
    ao[h0]     = t0 / s0;
    ao[h0 + 4] = t1 / s1;
}

// ---------------- one PPR hop: wide-gather layout ----------------
// Wave = 1 node. lane = (grp = lane>>4 -> edge subgroup, dl = lane&15 -> dim block of 8).
// 4 iters x 16B bf16x8 gather (4 rows in flight / wave-instruction), then
// shfl_xor(16,32) tree-reduce over the 4 edge groups; group 0 does alpha-mix + store.
__global__ __launch_bounds__(256) void hop_kernel(
        const short* __restrict__ fin, const float* __restrict__ fe,
        const float* __restrict__ av, const int* __restrict__ src,
        short* __restrict__ fout_b, float* __restrict__ fout_f, int n) {
    __shared__ int sidx[4 * DEG];
    int wv   = threadIdx.x >> 6;
    int lane = threadIdx.x & 63;
    int wid  = blockIdx.x * 4 + wv;
    if (threadIdx.x < 4 * DEG) {
        int node = blockIdx.x * 4 + (threadIdx.x >> 4);
        sidx[threadIdx.x] = (node < n) ? src[(size_t)node * DEG + (threadIdx.x & 15)] : 0;
    }
    __syncthreads();
    if (wid >= n) return;
    int grp = lane >> 4;     // edge subgroup 0..3
    int dl  = lane & 15;     // dim block: dims [dl*8, dl*8+8)
    int h   = dl >> 1;       // head covering these dims
    const float* ae = av + (size_t)wid * (DEG * NH);
    float acc[8] = {};
#pragma unroll
    for (int it = 0; it < 4; ++it) {
        int e = it * 4 + grp;
        int s = sidx[wv * DEG + e];
        float w = ae[e * NH + h];
        u32x4 v = *(const u32x4*)(fin + (size_t)s * DIN + dl * 8);
#pragma unroll
        for (int k = 0; k < 4; ++k) {
            acc[2 * k]     += w * bflo(v[k]);
            acc[2 * k + 1] += w * bfhi(v[k]);
        }
    }
#pragma unroll
    for (int k = 0; k < 8; ++k) {
        acc[k] += __shfl_xor(acc[k], 16, 64);
        acc[k] += __shfl_xor(acc[k], 32, 64);
    }
    if (grp == 0) {
        const float* fp = fe + (size_t)wid * DIN + dl * 8;
        float o[8];
#pragma unroll
        for (int k = 0; k < 8; ++k)
            o[k] = (1.f - ALPHA) * acc[k] + ALPHA * fp[k];
        if (fout_b) {
            unsigned pk[4];
#pragma unroll
            for (int k = 0; k < 4; ++k)
                pk[k] = f2bf(o[2 * k]) | (f2bf(o[2 * k + 1]) << 16);
            *(u32x4*)(fout_b + (size_t)wid * DIN + dl * 8) = *(u32x4*)pk;
        } else {
            float4 a = { o[0], o[1], o[2], o[3] };
            float4 b = { o[4], o[5], o[6], o[7] };
            *(float4*)(fout_f + (size_t)wid * DIN + dl * 8)     = a;
            *(float4*)(fout_f + (size_t)wid * DIN + dl * 8 + 4) = b;
        }
    }
}

extern "C" void kernel_launch(void* const* d_in, const int* in_sizes, int n_in,
                              void* d_out, int out_size, void* d_ws, size_t ws_size,
                              hipStream_t stream) {
    const float* feat   = (const float*)d_in[0];
    const float* Wh     = (const float*)d_in[1];
    const float* Wt     = (const float*)d_in[2];
    const float* We     = (const float*)d_in[3];
    const float* attn_p = (const float*)d_in[4];
    const float* g_head = (const float*)d_in[5];
    const float* g_tail = (const float*)d_in[6];
    const float* ln1_g  = (const float*)d_in[7];
    const float* ln1_b  = (const float*)d_in[8];
    const float* ln2_g  = (const float*)d_in[9];
    const float* ln2_b  = (const float*)d_in[10];
    const float* W1     = (const float*)d_in[11];
    const float* b1     = (const float*)d_in[12];
    const float* W2     = (const float*)d_in[13];
    const float* b2     = (const float*)d_in[14];
    const int*   src    = (const int*)d_in[15];
    // d_in[16] = dst: structurally repeat(arange(N), DEG) — exploited, not read

    float* ws = (float*)d_ws;
    // fp32 buffers
    float* fe   = ws;                  // [N,128]             0 .. 5.12M
    float* av   = ws + 5120000;        // [E,8]               .. 10.24M
    float* gh   = ws + 10240000;       // [N,8]               .. 10.56M
    float* gt   = ws + 10560000;       // [N,8]               .. 10.88M
    // bf16 buffers (float-offset base, cast)
    short* h_bf   = (short*)(ws + 10880000);  // [N,128]b .. 13.44M
    short* fh_bf  = (short*)(ws + 13440000);  // [N,128]b .. 16.00M
    short* ftl_bf = (short*)(ws + 16000000);  // [N,128]b .. 18.56M
    short* fe_bf  = (short*)(ws + 18560000);  // [N,128]b .. 21.12M
    short* f0_bf  = (short*)(ws + 21120000);  // [N,128]b .. 23.68M
    short* f1_bf  = (short*)(ws + 23680000);  // [N,128]b .. 26.24M
    float* ffin   = ws + 26240000;            // [N,128]f .. 31.36M (hop5 out)
    short* x_bf   = (short*)(ws + 31360000);  // [N,128]b .. 33.92M
    short* hidden = (short*)ws;               // [N,512]b overlays fe+av (dead by FFN)
    short* wb     = (short*)(ws + 33920000);  // weights bf16: 180224 shorts
    short* wh_bf = wb, *wt_bf = wb + 16384, *we_bf = wb + 32768;
    short* w1_bf = wb + 49152, *w2_bf = wb + 114688;
    float* rst = (float*)d_out;

    dim3 b256(256);
    int nodeBlocks  = (N_NODES * 64) / 256;  // 10000
    int nodeBlocks4 = (N_NODES + 3) / 4;

    cvt_weights<<<704, b256, 0, stream>>>(Wh, Wt, We, W1, W2, wh_bf, wt_bf, we_bf, w1_bf, w2_bf);
    ln_kernel<<<nodeBlocks, b256, 0, stream>>>(feat, ln1_g, ln1_b, h_bf, N_NODES);

    dim3 gp(N_NODES / 64, 1);
    mfma_gemm<<<gp, b256, 0, stream>>>(h_bf, wh_bf, N_NODES, DIN, DIN, nullptr, nullptr, 0, nullptr, fh_bf);
    mfma_gemm<<<gp, b256, 0, stream>>>(h_bf, wt_bf, N_NODES, DIN, DIN, nullptr, nullptr, 0, nullptr, ftl_bf);
    mfma_gemm<<<gp, b256, 0, stream>>>(h_bf, we_bf, N_NODES, DIN, DIN, nullptr, nullptr, 0, fe, fe_bf);

    gates_kernel<<<(N_NODES * NH) / 256, b256, 0, stream>>>(fh_bf, ftl_bf, g_head, g_tail, gh, gt, N_NODES * NH);
    attn_kernel<<<nodeBlocks, b256, 0, stream>>>(fh_bf, ftl_bf, gh, gt, attn_p, src, av, N_NODES);

    hop_kernel<<<nodeBlocks4, b256, 0, stream>>>(fe_bf, fe, av, src, f0_bf, nullptr, N_NODES);
    hop_kernel<<<nodeBlocks4, b256, 0, stream>>>(f0_bf, fe, av, src, f1_bf, nullptr, N_NODES);
    hop_kernel<<<nodeBlocks4, b256, 0, stream>>>(f1_bf, fe, av, src, f0_bf, nullptr, N_NODES);
    hop_kernel<<<nodeBlocks4, b256, 0, stream>>>(f0_bf, fe, av, src, f1_bf, nullptr, N_NODES);
    hop_kernel<<<nodeBlocks4, b256, 0, stream>>>(f1_bf, fe, av, src, nullptr, ffin, N_NODES);

    add_ln_kernel<<<nodeBlocks, b256, 0, stream>>>(ffin, feat, ln2_g, ln2_b, rst, x_bf, N_NODES);

    dim3 gff1(N_NODES / 64, FFDIM / 128);
    mfma_gemm<<<gff1, b256, 0, stream>>>(x_bf, w1_bf, N_NODES, FFDIM, DIN, b1, nullptr, 1, nullptr, hidden);
    dim3 gff2(N_NODES / 64, 1);
    mfma_gemm<<<gff2, b256, 0, stream>>>(hidden, w2_bf, N_NODES, DIN, FFDIM, b2, rst, 0, rst, nullptr);
}